// Round 8
// baseline (458.568 us; speedup 1.0000x reference)
//
#include <hip/hip_runtime.h>

#define NALGOS 64
#define NTASKS 1024
#define LXLEN  512
#define TOUT   (LXLEN + 1)   // 513
#define PROWS  (LXLEN + 8)   // 8 pad rows for phase1's t+8 prefetch overrun

__device__ __forceinline__ float rdlane(float v, int lane) {
    return __int_as_float(__builtin_amdgcn_readlane(__float_as_int(v), lane));
}

// ---------------------------------------------------------------------------
// Phase 0: materialize P'[t][l][k] = tm[lx[t]][lx[64k+l]] (TRANSPOSED row
// layout, 512 floats/row). Per-thread k is now CONTIGUOUS so phase1's refill
// is 2x dwordx4 instead of 8x dword (the 8-load form hit the vmcnt=63 cap:
// 8 loads x 8-step pipeline distance = 64 outstanding -> forced early waits
// inside the serial chain). Thread i handles columns i and i+256:
// l = i&63, k = i>>6 and (i>>6)+4.
// ---------------------------------------------------------------------------
__global__ __launch_bounds__(256) void phase0_kernel(
    const int* __restrict__ lx, const float* __restrict__ tm,
    float* __restrict__ P)
{
    const int t = blockIdx.x;          // 0..PROWS-1
    const int i = threadIdx.x;
    const int l = i & 63, k = i >> 6;
    if (t < LXLEN) {
        const int row = lx[t] * NTASKS;
        P[t * LXLEN + l * 8 + k]     = tm[row + lx[i]];
        P[t * LXLEN + l * 8 + k + 4] = tm[row + lx[i + 256]];
    } else {                            // pad rows: loaded by phase1, unused
        P[t * LXLEN + i]       = 0.f;
        P[t * LXLEN + i + 256] = 0.f;
    }
}

// ---------------------------------------------------------------------------
// Phase 1: per-algo scalar coefficient chain. One wave per algo, 64 blocks.
// PDEPTH=8 (exact; PDEPTH=16 spilled at the 92-VGPR heuristic cap -- do not
// revisit). Chain (r5): coef = (eff-boost) + 2*boost*rcp(1+e), saturates
// correctly at e->0/Inf, no clamp needed.
// THIS ROUND: refill reads the transposed P' as 2x float4 straight into
// G[j][*] registers -- 4x fewer load instrs in the serial chain, vmcnt
// pressure 64 -> 16 outstanding.
// ---------------------------------------------------------------------------
__global__ __launch_bounds__(64) void phase1_kernel(
    const int*   __restrict__ lx,
    const float* __restrict__ P,
    const float* __restrict__ diff,
    const float* __restrict__ eff_g,
    const float* __restrict__ mem_g,
    const float* __restrict__ boost_g,
    float*       __restrict__ coef_out)
{
    const int a = blockIdx.x, lane = threadIdx.x;

    float nk[8]; float V[8];
    #pragma unroll
    for (int k = 0; k < 8; ++k) {
        const int tsk = lx[lane + 64 * k];
        nk[k] = -1.4426950408889634f / diff[tsk];
        V[k] = 0.f;
    }
    const float eff = eff_g[a], mem = mem_g[a], boost = boost_g[a];
    const float twob = 2.f * boost, effmb = eff - boost;

    // prime 8-deep row pipeline: G[d][k] = P'[d][lane][k], d = 0..7
    float G[8][8];
    #pragma unroll
    for (int d = 0; d < 8; ++d) {
        const float4 v0 = *(const float4*)&P[d * LXLEN + lane * 8];
        const float4 v1 = *(const float4*)&P[d * LXLEN + lane * 8 + 4];
        G[d][0] = v0.x; G[d][1] = v0.y; G[d][2] = v0.z; G[d][3] = v0.w;
        G[d][4] = v1.x; G[d][5] = v1.y; G[d][6] = v1.z; G[d][7] = v1.w;
    }

    float coef = eff;
    float* cout = coef_out + (size_t)a * LXLEN;

    #pragma unroll
    for (int q = 0; q < 8; ++q) {
        float cbuf = 0.f;
        for (int g = 0; g < 8; ++g) {
            const int tb = q * 64 + g * 8;
            #pragma unroll
            for (int j = 0; j < 8; ++j) {
                // ---- serial chain ----
                const float p = V[q] * nk[q];
                const float x = rdlane(p, g * 8 + j);   // uniform lane select
                const float e = __builtin_exp2f(x);     // Inf/0 both safe
                const float w = __builtin_amdgcn_rcpf(1.f + e);
                coef = __builtin_fmaf(twob, w, effmb);
                cbuf = (lane == g * 8 + j) ? coef : cbuf;
                // ---- V update, future regs only ----
                #pragma unroll
                for (int k = q; k < 8; ++k)
                    V[k] = __builtin_fmaf(V[k], mem, G[j][k] * coef);
                // ---- refill row t+8: 2x dwordx4, contiguous per-thread ----
                const float* rp = P + (tb + j + 8) * LXLEN + lane * 8;
                const float4 v0 = *(const float4*)rp;
                const float4 v1 = *(const float4*)(rp + 4);
                G[j][0] = v0.x; G[j][1] = v0.y; G[j][2] = v0.z; G[j][3] = v0.w;
                G[j][4] = v1.x; G[j][5] = v1.y; G[j][6] = v1.z; G[j][7] = v1.w;
            }
        }
        cout[q * 64 + lane] = cbuf;                   // coalesced, 1/chunk
    }
}

// ---------------------------------------------------------------------------
// Phase 2: 2-algo-grouped bulk pass (r6 structure, passed). THIS ROUND:
// (a) sigmoid via sig = fma(2, rcp(1+e), -1) -- clamp dropped (exact
//     saturation at e->0/Inf, same algebra phase1 has used since r5);
// (b) ring stride 257 -> 258: flush-read bank index (2*lq+qq+..)&31 is
//     2-way aliased (free, m136) instead of 4-way; slot writes stay
//     conflict-free (2*slot+tid spans banks).
// Grid = 32ag x 8c x 4seg = 1024 blocks x 256 thr, LDS 35.8 KB ->
// 4 blocks/CU = 16 waves/CU.
//   d(n) = (-n)&15; 16-slot ring slot(s) = (s-d)&15; per round rr, algo g:
//     1. sb[j<d] -> slots [16-d,16)  (completes granule rr-1)
//     2. rr>=1: cooperative flush: 16-lane groups store one sibling row's
//        contiguous 64B granule; c=7/gr=3 clipped per-lane (lq <= 16-dd).
//     3. rr<4: sb[j>=d] -> slots [0,16-d)
//   c=0 head [0,d) from regs at rr=0; c=7,d=0: u=512 = sb[0] at rr=4.
// Warm: c=0,1 exact; c>=2 warm=128 (mem^128 ~1e-12 approximation).
// ---------------------------------------------------------------------------
__global__ __launch_bounds__(256, 4) void phase2_kernel(
    const int*   __restrict__ lx,
    const float* __restrict__ tm,
    const float* __restrict__ diff,
    const float* __restrict__ mem_g,
    const float* __restrict__ coef,
    float*       __restrict__ out)
{
    const int b   = blockIdx.x;            // 1024 blocks: ag*32 + c*4 + seg
    const int ag  = b >> 5;                // 0..31
    const int c   = (b >> 2) & 7;
    const int seg = b & 3;
    const int tid = threadIdx.x;           // 0..255
    const int n   = (seg << 8) | tid;

    const int warm  = (c >= 2) ? 128 : 64 * c;   // c=0,1 exact; c>=2 approx
    const int t0    = 64 * c - 1 - warm;         // t of array index 0 (may be -1)
    const int nfill = warm + 96;

    __shared__ __align__(16) int   task_sh[224];
    __shared__ __align__(16) float coef_sh[2][224];     // 1.8 KB
    __shared__ __align__(16) float ring[2][16][258];    // 33.0 KB

    for (int i = tid; i < nfill; i += 256) {
        const int t = t0 + i;
        const bool ok = (t >= 0) && (t < LXLEN);
        task_sh[i] = ok ? lx[t] : 0;
        #pragma unroll
        for (int g = 0; g < 2; ++g)
            coef_sh[g][i] = ok ? coef[(ag * 2 + g) * LXLEN + t] : 0.f;
    }

    float memv[2];
    #pragma unroll
    for (int g = 0; g < 2; ++g) memv[g] = mem_g[ag * 2 + g];

    const float negkd = -1.4426950408889634f / diff[n];
    const int   d     = (16 - (n & 15)) & 15;   // granule phase of row n

    float r[2];
    #pragma unroll
    for (int g = 0; g < 2; ++g) r[g] = 0.f;

    // cooperative-flush lane roles (own wave only -> no barriers needed)
    const int wb = tid & 192;              // wave base thread
    const int lq = tid & 15;               // float within granule
    const int qq = (tid >> 4) & 3;         // quad id 0..3

    __syncthreads();

    float rbuf[16];
    #pragma unroll
    for (int j = 0; j < 16; ++j) {
        const int tk = __builtin_amdgcn_readfirstlane(task_sh[j]);
        rbuf[j] = tm[(size_t)tk * NTASKS + n];
    }

    // warmup: 2 parallel r-recurrences, rows loaded once, rolling pipeline
    for (int base = 0; base < warm; base += 16) {
        float nbuf[16];
        #pragma unroll
        for (int j = 0; j < 16; ++j) {
            const int tk = __builtin_amdgcn_readfirstlane(task_sh[base + 16 + j]);
            nbuf[j] = tm[(size_t)tk * NTASKS + n];
        }
        #pragma unroll
        for (int v = 0; v < 4; ++v) {
            #pragma unroll
            for (int g = 0; g < 2; ++g) {
                const float4 cq = *(const float4*)&coef_sh[g][base + 4 * v];
                const float mg = memv[g];
                r[g] = __builtin_fmaf(r[g], mg, rbuf[4 * v + 0] * cq.x);
                r[g] = __builtin_fmaf(r[g], mg, rbuf[4 * v + 1] * cq.y);
                r[g] = __builtin_fmaf(r[g], mg, rbuf[4 * v + 2] * cq.z);
                r[g] = __builtin_fmaf(r[g], mg, rbuf[4 * v + 3] * cq.w);
            }
        }
        #pragma unroll
        for (int j = 0; j < 16; ++j) rbuf[j] = nbuf[j];
    }

    // output: 5 rounds of 16 steps; step s = 16rr+j, out pos u = 64c+s,
    // recurrence t = u-1 (t=-1 dummy: task 0, coef 0 -> sig 0 at u=0).
    for (int rr = 0; rr < 5; ++rr) {
        const int base = warm + 16 * rr;
        float nbuf[16];
        #pragma unroll
        for (int j = 0; j < 16; ++j) {
            const int tk = __builtin_amdgcn_readfirstlane(task_sh[base + 16 + j]);
            nbuf[j] = tm[(size_t)tk * NTASKS + n];
        }
        #pragma unroll
        for (int g = 0; g < 2; ++g) {
            const float mg = memv[g];
            float sb[16];
            #pragma unroll
            for (int v = 0; v < 4; ++v) {
                const float4 cq = *(const float4*)&coef_sh[g][base + 4 * v];
                const float cf[4] = { cq.x, cq.y, cq.z, cq.w };
                #pragma unroll
                for (int u4 = 0; u4 < 4; ++u4) {
                    const int j = 4 * v + u4;
                    r[g] = __builtin_fmaf(r[g], mg, rbuf[j] * cf[u4]);
                    const float e = __builtin_exp2f(r[g] * negkd);
                    const float w = __builtin_amdgcn_rcpf(1.f + e);
                    sb[j] = __builtin_fmaf(2.f, w, -1.f);
                }
            }
            float* ringc = &ring[g][0][0] + tid;   // own column, stride 258
            // 1. complete granule rr-1: j<d -> slots [16-d,16)
            #pragma unroll
            for (int j = 0; j < 15; ++j)
                if (j < d) ringc[(j + 16 - d) * 258] = sb[j];
            // 2. cooperative flush of granule rr-1
            if (rr >= 1) {
                const int gr = rr - 1;
                float* outg = out + (size_t)(ag * 2 + g) * NTASKS * TOUT;
                #pragma unroll
                for (int sub = 0; sub < 16; ++sub) {
                    const int tau = wb + 4 * sub + qq;      // sibling thread
                    const int nn  = (seg << 8) | tau;       // its row
                    const int dd  = (16 - (tau & 15)) & 15; // its phase
                    const float vv = ring[g][lq][tau];
                    if (!(c == 7 && gr == 3 && lq > 16 - dd))
                        outg[(size_t)nn * TOUT + 64 * c + dd + 16 * gr + lq] = vv;
                }
            }
            // 3. start granule rr: j>=d -> slots [0,16-d)  (skip last round)
            if (rr < 4) {
                #pragma unroll
                for (int j = 0; j < 16; ++j)
                    if (j >= d) ringc[(j - d) * 258] = sb[j];
            }
            // ragged partials
            if (c == 0 && rr == 0) {
                float* rowp = out + ((size_t)(ag * 2 + g) * NTASKS + n) * TOUT;
                #pragma unroll
                for (int j = 0; j < 15; ++j)
                    if (j < d) rowp[j] = sb[j];
            }
            if (c == 7 && rr == 4 && d == 0) {
                float* rowp = out + ((size_t)(ag * 2 + g) * NTASKS + n) * TOUT;
                rowp[512] = sb[0];
            }
        }
        #pragma unroll
        for (int j = 0; j < 16; ++j) rbuf[j] = nbuf[j];
    }
}

// ---------------------------------------------------------------------------
// Fallback (validated R1 kernel): used only if ws can't hold coef + P.
// ---------------------------------------------------------------------------
__global__ __launch_bounds__(1024) void fused_fallback_kernel(
    const int* __restrict__ lx, const float* __restrict__ tm,
    const float* __restrict__ diff, const float* __restrict__ eff_g,
    const float* __restrict__ mem_g, const float* __restrict__ boost_g,
    float* __restrict__ out)
{
    const int a = blockIdx.x, n = threadIdx.x;
    __shared__ int lx_sh[LXLEN];
    __shared__ float sbuf[2];
    if (n < LXLEN) lx_sh[n] = lx[n];
    if (n == 0) sbuf[0] = 0.0f;
    const float eff = eff_g[a], mem = mem_g[a], boost = boost_g[a];
    const float negkd = -1.4426950408889634f / diff[n];
    float* outp = out + ((size_t)a * NTASKS + n) * TOUT;
    outp[0] = 0.0f;
    float r = 0.0f;
    __syncthreads();
    for (int t = 0; t < LXLEN; ++t) {
        const int task = lx_sh[t];
        const float s = sbuf[t & 1];
        const float coef = __builtin_fmaf(s, boost, eff);
        const float row = tm[task * NTASKS + n];
        r = __builtin_fmaf(r, mem, row * coef);
        float x = r * negkd;
        x = fminf(fmaxf(x, -126.0f), 126.0f);
        const float e = __builtin_exp2f(x);
        const float sig = (1.0f - e) * __builtin_amdgcn_rcpf(1.0f + e);
        outp[t + 1] = sig;
        if (t + 1 < LXLEN && n == lx_sh[t + 1]) sbuf[(t + 1) & 1] = sig;
        __syncthreads();
    }
}

extern "C" void kernel_launch(void* const* d_in, const int* in_sizes, int n_in,
                              void* d_out, int out_size, void* d_ws, size_t ws_size,
                              hipStream_t stream) {
    const int*   lx    = (const int*)  d_in[0];
    const float* tm    = (const float*)d_in[1];
    const float* diff  = (const float*)d_in[2];
    const float* eff   = (const float*)d_in[3];
    const float* mem   = (const float*)d_in[4];
    const float* boost = (const float*)d_in[5];
    float* out = (float*)d_out;

    const size_t coef_elems = (size_t)NALGOS * LXLEN;
    const size_t P_elems    = (size_t)PROWS * LXLEN;
    const size_t need_bytes = (coef_elems + P_elems) * sizeof(float);

    if (ws_size >= need_bytes) {
        float* coef = (float*)d_ws;
        float* P    = coef + coef_elems;
        phase0_kernel<<<dim3(PROWS), dim3(256), 0, stream>>>(lx, tm, P);
        phase1_kernel<<<dim3(NALGOS), dim3(64), 0, stream>>>(
            lx, P, diff, eff, mem, boost, coef);
        phase2_kernel<<<dim3(1024), dim3(256), 0, stream>>>(
            lx, tm, diff, mem, coef, out);
    } else {
        fused_fallback_kernel<<<dim3(NALGOS), dim3(NTASKS), 0, stream>>>(
            lx, tm, diff, eff, mem, boost, out);
    }
}

// Round 9
// 223.018 us; speedup vs baseline: 2.0562x; 2.0562x over previous
//
#include <hip/hip_runtime.h>

#define NALGOS 64
#define NTASKS 1024
#define LXLEN  512
#define TOUT   (LXLEN + 1)   // 513
#define PROWS  (LXLEN + 8)   // 8 pad rows for phase1's t+8 prefetch overrun

__device__ __forceinline__ float rdlane(float v, int lane) {
    return __int_as_float(__builtin_amdgcn_readlane(__float_as_int(v), lane));
}

// ---------------------------------------------------------------------------
// Phase 0: materialize P[t][i] = tm[lx[t]][lx[i]] (512x512, 1 MB) with full
// parallelism so phase1's per-step loads become lane-coalesced.
// (r6 version restored -- the r7 transposed layout forced float4 quad-reg
// constraints in phase1 that ballooned VGPR to 256 and SPILLED: FETCH/WRITE
// +8 MB scratch traffic, 283 us. Scalar-refill version: 33 us, no spill.)
// ---------------------------------------------------------------------------
__global__ __launch_bounds__(256) void phase0_kernel(
    const int* __restrict__ lx, const float* __restrict__ tm,
    float* __restrict__ P)
{
    const int t = blockIdx.x;          // 0..PROWS-1
    const int i = threadIdx.x;
    if (t < LXLEN) {
        const int row = lx[t] * NTASKS;
        P[t * LXLEN + i]       = tm[row + lx[i]];
        P[t * LXLEN + i + 256] = tm[row + lx[i + 256]];
    } else {                            // pad rows: loaded by phase1, unused
        P[t * LXLEN + i]       = 0.f;
        P[t * LXLEN + i + 256] = 0.f;
    }
}

// ---------------------------------------------------------------------------
// Phase 1: per-algo scalar coefficient chain. One wave per algo, 64 blocks.
// r6 version restored (measured ~33 us, VGPR ~92, no spill). PDEPTH=8 exact;
// PDEPTH=16 spilled (r2/r3); float4-refill spilled at VGPR=256 (r8) -- do
// not revisit either. Chain (r5): coef = (eff-boost) + 2*boost*rcp(1+e),
// saturates correctly at e->0/Inf, no clamp needed.
// ---------------------------------------------------------------------------
__global__ __launch_bounds__(64) void phase1_kernel(
    const int*   __restrict__ lx,
    const float* __restrict__ P,
    const float* __restrict__ diff,
    const float* __restrict__ eff_g,
    const float* __restrict__ mem_g,
    const float* __restrict__ boost_g,
    float*       __restrict__ coef_out)
{
    const int a = blockIdx.x, lane = threadIdx.x;

    float nk[8]; float V[8];
    #pragma unroll
    for (int k = 0; k < 8; ++k) {
        const int tsk = lx[lane + 64 * k];
        nk[k] = -1.4426950408889634f / diff[tsk];
        V[k] = 0.f;
    }
    const float eff = eff_g[a], mem = mem_g[a], boost = boost_g[a];
    const float twob = 2.f * boost, effmb = eff - boost;

    // prime 8-deep row pipeline: G[d][k] = P[d][64k+lane], d = 0..7
    float G[8][8];
    #pragma unroll
    for (int d = 0; d < 8; ++d)
        #pragma unroll
        for (int k = 0; k < 8; ++k)
            G[d][k] = P[d * LXLEN + 64 * k + lane];

    float coef = eff;
    float* cout = coef_out + (size_t)a * LXLEN;

    #pragma unroll
    for (int q = 0; q < 8; ++q) {
        float cbuf = 0.f;
        for (int g = 0; g < 8; ++g) {
            const int tb = q * 64 + g * 8;
            #pragma unroll
            for (int j = 0; j < 8; ++j) {
                // ---- serial chain ----
                const float p = V[q] * nk[q];
                const float x = rdlane(p, g * 8 + j);   // uniform lane select
                const float e = __builtin_exp2f(x);     // Inf/0 both safe
                const float w = __builtin_amdgcn_rcpf(1.f + e);
                coef = __builtin_fmaf(twob, w, effmb);
                cbuf = (lane == g * 8 + j) ? coef : cbuf;
                // ---- V update, future regs only ----
                #pragma unroll
                for (int k = q; k < 8; ++k)
                    V[k] = __builtin_fmaf(V[k], mem, G[j][k] * coef);
                // ---- refill row t+8, lane-coalesced ----
                const float* rp = P + (tb + j + 8) * LXLEN + lane;
                #pragma unroll
                for (int k = q; k < 8; ++k)
                    G[j][k] = rp[64 * k];
            }
        }
        cout[q * 64 + lane] = cbuf;                   // coalesced, 1/chunk
    }
}

// ---------------------------------------------------------------------------
// Phase 2: 2-algo-grouped bulk pass (r8 version kept -- passed twice, and
// budget arithmetic shows the r7 tweaks saved ~15 us):
// (a) sigmoid via sig = fma(2, rcp(1+e), -1) -- clamp dropped (exact
//     saturation at e->0/Inf);
// (b) ring stride 258: flush-read bank aliasing 2-way (free) not 4-way.
// Grid = 32ag x 8c x 4seg = 1024 blocks x 256 thr, LDS 35.8 KB ->
// 4 blocks/CU = 16 waves/CU.
//   d(n) = (-n)&15; 16-slot ring slot(s) = (s-d)&15; per round rr, algo g:
//     1. sb[j<d] -> slots [16-d,16)  (completes granule rr-1)
//     2. rr>=1: cooperative flush: 16-lane groups store one sibling row's
//        contiguous 64B granule; c=7/gr=3 clipped per-lane (lq <= 16-dd).
//     3. rr<4: sb[j>=d] -> slots [0,16-d)
//   c=0 head [0,d) from regs at rr=0; c=7,d=0: u=512 = sb[0] at rr=4.
// Warm: c=0,1 exact; c>=2 warm=128 (mem^128 ~1e-12 approximation).
// ---------------------------------------------------------------------------
__global__ __launch_bounds__(256, 4) void phase2_kernel(
    const int*   __restrict__ lx,
    const float* __restrict__ tm,
    const float* __restrict__ diff,
    const float* __restrict__ mem_g,
    const float* __restrict__ coef,
    float*       __restrict__ out)
{
    const int b   = blockIdx.x;            // 1024 blocks: ag*32 + c*4 + seg
    const int ag  = b >> 5;                // 0..31
    const int c   = (b >> 2) & 7;
    const int seg = b & 3;
    const int tid = threadIdx.x;           // 0..255
    const int n   = (seg << 8) | tid;

    const int warm  = (c >= 2) ? 128 : 64 * c;   // c=0,1 exact; c>=2 approx
    const int t0    = 64 * c - 1 - warm;         // t of array index 0 (may be -1)
    const int nfill = warm + 96;

    __shared__ __align__(16) int   task_sh[224];
    __shared__ __align__(16) float coef_sh[2][224];     // 1.8 KB
    __shared__ __align__(16) float ring[2][16][258];    // 33.0 KB

    for (int i = tid; i < nfill; i += 256) {
        const int t = t0 + i;
        const bool ok = (t >= 0) && (t < LXLEN);
        task_sh[i] = ok ? lx[t] : 0;
        #pragma unroll
        for (int g = 0; g < 2; ++g)
            coef_sh[g][i] = ok ? coef[(ag * 2 + g) * LXLEN + t] : 0.f;
    }

    float memv[2];
    #pragma unroll
    for (int g = 0; g < 2; ++g) memv[g] = mem_g[ag * 2 + g];

    const float negkd = -1.4426950408889634f / diff[n];
    const int   d     = (16 - (n & 15)) & 15;   // granule phase of row n

    float r[2];
    #pragma unroll
    for (int g = 0; g < 2; ++g) r[g] = 0.f;

    // cooperative-flush lane roles (own wave only -> no barriers needed)
    const int wb = tid & 192;              // wave base thread
    const int lq = tid & 15;               // float within granule
    const int qq = (tid >> 4) & 3;         // quad id 0..3

    __syncthreads();

    float rbuf[16];
    #pragma unroll
    for (int j = 0; j < 16; ++j) {
        const int tk = __builtin_amdgcn_readfirstlane(task_sh[j]);
        rbuf[j] = tm[(size_t)tk * NTASKS + n];
    }

    // warmup: 2 parallel r-recurrences, rows loaded once, rolling pipeline
    for (int base = 0; base < warm; base += 16) {
        float nbuf[16];
        #pragma unroll
        for (int j = 0; j < 16; ++j) {
            const int tk = __builtin_amdgcn_readfirstlane(task_sh[base + 16 + j]);
            nbuf[j] = tm[(size_t)tk * NTASKS + n];
        }
        #pragma unroll
        for (int v = 0; v < 4; ++v) {
            #pragma unroll
            for (int g = 0; g < 2; ++g) {
                const float4 cq = *(const float4*)&coef_sh[g][base + 4 * v];
                const float mg = memv[g];
                r[g] = __builtin_fmaf(r[g], mg, rbuf[4 * v + 0] * cq.x);
                r[g] = __builtin_fmaf(r[g], mg, rbuf[4 * v + 1] * cq.y);
                r[g] = __builtin_fmaf(r[g], mg, rbuf[4 * v + 2] * cq.z);
                r[g] = __builtin_fmaf(r[g], mg, rbuf[4 * v + 3] * cq.w);
            }
        }
        #pragma unroll
        for (int j = 0; j < 16; ++j) rbuf[j] = nbuf[j];
    }

    // output: 5 rounds of 16 steps; step s = 16rr+j, out pos u = 64c+s,
    // recurrence t = u-1 (t=-1 dummy: task 0, coef 0 -> sig 0 at u=0).
    for (int rr = 0; rr < 5; ++rr) {
        const int base = warm + 16 * rr;
        float nbuf[16];
        #pragma unroll
        for (int j = 0; j < 16; ++j) {
            const int tk = __builtin_amdgcn_readfirstlane(task_sh[base + 16 + j]);
            nbuf[j] = tm[(size_t)tk * NTASKS + n];
        }
        #pragma unroll
        for (int g = 0; g < 2; ++g) {
            const float mg = memv[g];
            float sb[16];
            #pragma unroll
            for (int v = 0; v < 4; ++v) {
                const float4 cq = *(const float4*)&coef_sh[g][base + 4 * v];
                const float cf[4] = { cq.x, cq.y, cq.z, cq.w };
                #pragma unroll
                for (int u4 = 0; u4 < 4; ++u4) {
                    const int j = 4 * v + u4;
                    r[g] = __builtin_fmaf(r[g], mg, rbuf[j] * cf[u4]);
                    const float e = __builtin_exp2f(r[g] * negkd);
                    const float w = __builtin_amdgcn_rcpf(1.f + e);
                    sb[j] = __builtin_fmaf(2.f, w, -1.f);
                }
            }
            float* ringc = &ring[g][0][0] + tid;   // own column, stride 258
            // 1. complete granule rr-1: j<d -> slots [16-d,16)
            #pragma unroll
            for (int j = 0; j < 15; ++j)
                if (j < d) ringc[(j + 16 - d) * 258] = sb[j];
            // 2. cooperative flush of granule rr-1
            if (rr >= 1) {
                const int gr = rr - 1;
                float* outg = out + (size_t)(ag * 2 + g) * NTASKS * TOUT;
                #pragma unroll
                for (int sub = 0; sub < 16; ++sub) {
                    const int tau = wb + 4 * sub + qq;      // sibling thread
                    const int nn  = (seg << 8) | tau;       // its row
                    const int dd  = (16 - (tau & 15)) & 15; // its phase
                    const float vv = ring[g][lq][tau];
                    if (!(c == 7 && gr == 3 && lq > 16 - dd))
                        outg[(size_t)nn * TOUT + 64 * c + dd + 16 * gr + lq] = vv;
                }
            }
            // 3. start granule rr: j>=d -> slots [0,16-d)  (skip last round)
            if (rr < 4) {
                #pragma unroll
                for (int j = 0; j < 16; ++j)
                    if (j >= d) ringc[(j - d) * 258] = sb[j];
            }
            // ragged partials
            if (c == 0 && rr == 0) {
                float* rowp = out + ((size_t)(ag * 2 + g) * NTASKS + n) * TOUT;
                #pragma unroll
                for (int j = 0; j < 15; ++j)
                    if (j < d) rowp[j] = sb[j];
            }
            if (c == 7 && rr == 4 && d == 0) {
                float* rowp = out + ((size_t)(ag * 2 + g) * NTASKS + n) * TOUT;
                rowp[512] = sb[0];
            }
        }
        #pragma unroll
        for (int j = 0; j < 16; ++j) rbuf[j] = nbuf[j];
    }
}

// ---------------------------------------------------------------------------
// Fallback (validated R1 kernel): used only if ws can't hold coef + P.
// ---------------------------------------------------------------------------
__global__ __launch_bounds__(1024) void fused_fallback_kernel(
    const int* __restrict__ lx, const float* __restrict__ tm,
    const float* __restrict__ diff, const float* __restrict__ eff_g,
    const float* __restrict__ mem_g, const float* __restrict__ boost_g,
    float* __restrict__ out)
{
    const int a = blockIdx.x, n = threadIdx.x;
    __shared__ int lx_sh[LXLEN];
    __shared__ float sbuf[2];
    if (n < LXLEN) lx_sh[n] = lx[n];
    if (n == 0) sbuf[0] = 0.0f;
    const float eff = eff_g[a], mem = mem_g[a], boost = boost_g[a];
    const float negkd = -1.4426950408889634f / diff[n];
    float* outp = out + ((size_t)a * NTASKS + n) * TOUT;
    outp[0] = 0.0f;
    float r = 0.0f;
    __syncthreads();
    for (int t = 0; t < LXLEN; ++t) {
        const int task = lx_sh[t];
        const float s = sbuf[t & 1];
        const float coef = __builtin_fmaf(s, boost, eff);
        const float row = tm[task * NTASKS + n];
        r = __builtin_fmaf(r, mem, row * coef);
        float x = r * negkd;
        x = fminf(fmaxf(x, -126.0f), 126.0f);
        const float e = __builtin_exp2f(x);
        const float sig = (1.0f - e) * __builtin_amdgcn_rcpf(1.0f + e);
        outp[t + 1] = sig;
        if (t + 1 < LXLEN && n == lx_sh[t + 1]) sbuf[(t + 1) & 1] = sig;
        __syncthreads();
    }
}

extern "C" void kernel_launch(void* const* d_in, const int* in_sizes, int n_in,
                              void* d_out, int out_size, void* d_ws, size_t ws_size,
                              hipStream_t stream) {
    const int*   lx    = (const int*)  d_in[0];
    const float* tm    = (const float*)d_in[1];
    const float* diff  = (const float*)d_in[2];
    const float* eff   = (const float*)d_in[3];
    const float* mem   = (const float*)d_in[4];
    const float* boost = (const float*)d_in[5];
    float* out = (float*)d_out;

    const size_t coef_elems = (size_t)NALGOS * LXLEN;
    const size_t P_elems    = (size_t)PROWS * LXLEN;
    const size_t need_bytes = (coef_elems + P_elems) * sizeof(float);

    if (ws_size >= need_bytes) {
        float* coef = (float*)d_ws;
        float* P    = coef + coef_elems;
        phase0_kernel<<<dim3(PROWS), dim3(256), 0, stream>>>(lx, tm, P);
        phase1_kernel<<<dim3(NALGOS), dim3(64), 0, stream>>>(
            lx, P, diff, eff, mem, boost, coef);
        phase2_kernel<<<dim3(1024), dim3(256), 0, stream>>>(
            lx, tm, diff, mem, coef, out);
    } else {
        fused_fallback_kernel<<<dim3(NALGOS), dim3(NTASKS), 0, stream>>>(
            lx, tm, diff, eff, mem, boost, out);
    }
}